// Round 4
// baseline (226.325 us; speedup 1.0000x reference)
//
#include <hip/hip_runtime.h>
#include <math.h>

typedef short short8 __attribute__((ext_vector_type(8)));
typedef float f32x4 __attribute__((ext_vector_type(4)));
typedef float f32x16 __attribute__((ext_vector_type(16)));

__device__ __forceinline__ float2 cmul(float2 a, float2 b) {
    return make_float2(a.x * b.x - a.y * b.y, a.x * b.y + a.y * b.x);
}

__device__ __forceinline__ ushort f2bf(float f) {
    uint u = __float_as_uint(f);
    uint r = (u + 0x7FFFu + ((u >> 16) & 1u)) >> 16;
    return (ushort)r;
}

// ---- prep: conv2 weights -> wt2[tap][icg][oc][ic8] bf16 ; fc1 weights -> bf16 ----
__global__ __launch_bounds__(256) void prep_kernel(
    const float* __restrict__ c2w, const float* __restrict__ f1w,
    ushort* __restrict__ wt2, ushort* __restrict__ wf1)
{
    int i = blockIdx.x * 256 + threadIdx.x;
    if (i < 18432) {
        int icl = i & 7;
        int t = i >> 3;
        int oc = t & 63;
        int t2 = t >> 6;
        int icg = t2 & 3;
        int tap = t2 >> 2;
        int ic = icg * 8 + icl;
        wt2[i] = f2bf(c2w[(oc * 32 + ic) * 9 + tap]);
    } else if (i < 18432 + 1179648) {
        int j = i - 18432;
        wf1[j] = f2bf(f1w[j]);
    }
}

// ---- fused conv1+relu -> (LDS) -> conv2 MFMA + bias + relu + shfl-maxpool ----
// one block per image, 384 thr = 6 waves.
// conv1: 26x26x32 bf16 tile computed in-LDS.  conv2: 9 taps x GEMM(64oc x 576px x 32ic).
// pixel map: 24x24 conv2 grid as 18 regions of 8x4; region r=wid*3+i, rx=r%3, ry=r/3,
//   x = rx*8+(lo&7), y = ry*4+(lo>>3).  pool partners: lane^1 (x+1), lane^8 (y+1).
__global__ __launch_bounds__(384, 3) void conv2_fused(
    const float* __restrict__ x, const float* __restrict__ w1,
    const float* __restrict__ b1, const ushort* __restrict__ wt2,
    const float* __restrict__ c2b, ushort* __restrict__ pooled)
{
    __shared__ ushort h1s[21632];   // [icg][pix][ic8] bf16, 43,264 B
    __shared__ float xs[784];
    __shared__ float w1s[288];
    __shared__ float b1s[32];
    __shared__ float b2s[64];
    int b = blockIdx.x;
    int tid = threadIdx.x;

    // stage x image + conv1 weights/biases + conv2 bias (all uint4)
    if (tid < 196) {
        ((uint4*)xs)[tid] = ((const uint4*)(x + (size_t)b * 784))[tid];
    } else if (tid < 268) {
        ((uint4*)w1s)[tid - 196] = ((const uint4*)w1)[tid - 196];
    } else if (tid < 276) {
        ((uint4*)b1s)[tid - 268] = ((const uint4*)b1)[tid - 268];
    } else if (tid < 292) {
        ((uint4*)b2s)[tid - 276] = ((const uint4*)c2b)[tid - 276];
    }
    __syncthreads();

    // conv1 + relu -> h1s (identical math to the old conv1 kernel)
    for (int it = 0; it < 8; ++it) {
        int task = tid + it * 384;
        if (task >= 2704) break;
        int icg = task & 3;
        int pix = task >> 2;
        int yr = pix / 26, xc = pix % 26;
        float in9[9];
#pragma unroll
        for (int ky = 0; ky < 3; ++ky)
#pragma unroll
            for (int kx = 0; kx < 3; ++kx)
                in9[ky * 3 + kx] = xs[(yr + ky) * 28 + xc + kx];
        short8 ov;
#pragma unroll
        for (int o = 0; o < 8; ++o) {
            int oc = icg * 8 + o;
            float acc = b1s[oc];
#pragma unroll
            for (int k = 0; k < 9; ++k) acc = fmaf(in9[k], w1s[oc * 9 + k], acc);
            ov[o] = (short)f2bf(fmaxf(acc, 0.f));
        }
        *(short8*)&h1s[(icg * 676 + pix) * 8] = ov;
    }
    __syncthreads();

    int wid = tid >> 6;
    int lane = tid & 63;
    int lo = lane & 31;
    int hi = lane >> 5;

    int boff[3];
#pragma unroll
    for (int i = 0; i < 3; ++i) {
        int r_idx = wid * 3 + i;
        int rx = r_idx % 3, ry = r_idx / 3;
        int xcoord = rx * 8 + (lo & 7);
        int ycoord = ry * 4 + (lo >> 3);
        boff[i] = (ycoord * 26 + xcoord) * 8;
    }

    f32x16 acc[2][3];
#pragma unroll
    for (int mt = 0; mt < 2; ++mt)
#pragma unroll
        for (int i = 0; i < 3; ++i) acc[mt][i] = (f32x16)0.f;

#pragma unroll
    for (int tap = 0; tap < 9; ++tap) {
        int toff = ((tap / 3) * 26 + (tap % 3)) * 8;
        short8 a[2][2];
#pragma unroll
        for (int mt = 0; mt < 2; ++mt)
#pragma unroll
            for (int ks = 0; ks < 2; ++ks)
                a[mt][ks] = *(const short8*)(wt2 +
                    ((tap * 4 + ks * 2 + hi) * 64 + mt * 32 + lo) * 8);
#pragma unroll
        for (int i = 0; i < 3; ++i) {
#pragma unroll
            for (int ks = 0; ks < 2; ++ks) {
                short8 bf = *(const short8*)&h1s[(ks * 2 + hi) * 5408 + boff[i] + toff];
                acc[0][i] = __builtin_amdgcn_mfma_f32_32x32x16_bf16(a[0][ks], bf, acc[0][i], 0, 0, 0);
                acc[1][i] = __builtin_amdgcn_mfma_f32_32x32x16_bf16(a[1][ks], bf, acc[1][i], 0, 0, 0);
            }
        }
    }

    // epilogue: bias + relu + 2x2 maxpool via shfl, packed bf16-pair stores
    ushort* pout = pooled + (size_t)b * 9216;
#pragma unroll
    for (int mt = 0; mt < 2; ++mt)
#pragma unroll
        for (int i = 0; i < 3; ++i) {
            int r_idx = wid * 3 + i;
            int rx = r_idx % 3, ry = r_idx / 3;
#pragma unroll
            for (int r = 0; r < 16; ++r) {
                int oc = mt * 32 + (r & 3) + 8 * (r >> 2) + 4 * hi;
                float v = fmaxf(acc[mt][i][r] + b2s[oc], 0.f);
                float m = fmaxf(v, __shfl_xor(v, 1, 64));
                m = fmaxf(m, __shfl_xor(m, 8, 64));
                float mp = __shfl_xor(m, 2, 64);
                if ((lo & 0xB) == 0) {   // lo in {0,4,16,20}: x,y even, x%4==0
                    uint pk = (uint)f2bf(m) | ((uint)f2bf(mp) << 16);
                    int pxp = rx * 4 + ((lo >> 1) & 3);      // 0 or 2 within region
                    int py = ry * 2 + ((lo >> 4) & 1);
                    *(uint*)&pout[oc * 144 + py * 12 + pxp] = pk;
                }
            }
        }
}

// ---- fc1 MFMA: pooled[2048,9216]bf16 x wf1[128,9216]bf16^T, 4-way K-split ----
__global__ __launch_bounds__(256) void fc1_mfma(
    const ushort* __restrict__ pooled, const ushort* __restrict__ wf1,
    float* __restrict__ part)
{
    int bx = blockIdx.x, by = blockIdx.y;
    int tid = threadIdx.x;
    int wid = tid >> 6, lane = tid & 63;
    int lo = lane & 15, hi = lane >> 4;
    int m0 = bx * 32;
    int kb = by * 2304;

    f32x4 acc[2][2];
#pragma unroll
    for (int mt = 0; mt < 2; ++mt)
#pragma unroll
        for (int j = 0; j < 2; ++j) acc[mt][j] = (f32x4)0.f;

    const ushort* arow0 = pooled + (size_t)(m0 + lo) * 9216 + kb + hi * 8;
    const ushort* arow1 = arow0 + 16 * 9216;
    const ushort* brow0 = wf1 + (size_t)(wid * 32 + lo) * 9216 + kb + hi * 8;
    const ushort* brow1 = brow0 + 16 * 9216;

    for (int kt = 0; kt < 72; ++kt) {
        short8 a0 = *(const short8*)(arow0 + kt * 32);
        short8 a1 = *(const short8*)(arow1 + kt * 32);
        short8 b0 = *(const short8*)(brow0 + kt * 32);
        short8 b1 = *(const short8*)(brow1 + kt * 32);
        acc[0][0] = __builtin_amdgcn_mfma_f32_16x16x32_bf16(a0, b0, acc[0][0], 0, 0, 0);
        acc[1][0] = __builtin_amdgcn_mfma_f32_16x16x32_bf16(a1, b0, acc[1][0], 0, 0, 0);
        acc[0][1] = __builtin_amdgcn_mfma_f32_16x16x32_bf16(a0, b1, acc[0][1], 0, 0, 0);
        acc[1][1] = __builtin_amdgcn_mfma_f32_16x16x32_bf16(a1, b1, acc[1][1], 0, 0, 0);
    }
    float* pp = part + (size_t)by * 262144;
#pragma unroll
    for (int mt = 0; mt < 2; ++mt)
#pragma unroll
        for (int j = 0; j < 2; ++j)
#pragma unroll
            for (int r = 0; r < 4; ++r)
                pp[(m0 + mt * 16 + hi * 4 + r) * 128 + wid * 32 + j * 16 + lo] = acc[mt][j][r];
}

__global__ __launch_bounds__(256) void fc1_reduce_kernel(
    const float* __restrict__ part, const float* __restrict__ bias,
    float* __restrict__ outp)
{
    int idx = blockIdx.x * 256 + threadIdx.x;   // < 262144
    float s = 0.f;
#pragma unroll
    for (int ks = 0; ks < 4; ++ks) s += part[ks * 262144 + idx];
    outp[idx] = fmaxf(s + bias[idx & 127], 0.f);
}

// ---- fc2 + sigmoid*2pi -> angles[2048,10] ----
__global__ __launch_bounds__(256) void fc2_kernel(
    const float* __restrict__ h, const float* __restrict__ w,
    const float* __restrict__ bias, float* __restrict__ ang)
{
    int idx = blockIdx.x * 256 + threadIdx.x;
    if (idx >= 20480) return;
    int b = idx / 10, n = idx % 10;
    const float* hp = h + b * 128;
    const float* wp = w + n * 128;
    float s = bias[n];
    for (int k = 0; k < 128; ++k) s = fmaf(hp[k], wp[k], s);
    ang[idx] = 6.28318530718f / (1.f + expf(-s));
}

// ---------------- quantum circuit + <Y_k> + log_softmax ----------------
__device__ __forceinline__ void apply_rot(float2* s, int p, float phi, float th,
                                          float om, int tid)
{
    float c, sn; sincosf(0.5f * th, &sn, &c);
    float A = 0.5f * (phi + om), Bv = 0.5f * (phi - om);
    float cA, sA; sincosf(A, &sA, &cA);
    float cB, sB; sincosf(Bv, &sB, &cB);
    float2 m00 = make_float2(cA * c, -sA * c);
    float2 m01 = make_float2(-cB * sn, -sB * sn);
    float2 m10 = make_float2(cB * sn, -sB * sn);
    float2 m11 = make_float2(cA * c, sA * c);
    for (int q = tid; q < 512; q += 256) {
        int i0 = ((q >> p) << (p + 1)) | (q & ((1 << p) - 1));
        int i1 = i0 | (1 << p);
        float2 aa = s[i0], bb = s[i1];
        s[i0] = make_float2(m00.x * aa.x - m00.y * aa.y + m01.x * bb.x - m01.y * bb.y,
                            m00.x * aa.y + m00.y * aa.x + m01.x * bb.y + m01.y * bb.x);
        s[i1] = make_float2(m10.x * aa.x - m10.y * aa.y + m11.x * bb.x - m11.y * bb.y,
                            m10.x * aa.y + m10.y * aa.x + m11.x * bb.y + m11.y * bb.x);
    }
}

__global__ __launch_bounds__(256) void quantum_kernel(
    const float* __restrict__ ang, const float* __restrict__ theta0,
    const float* __restrict__ theta_rz, const float* __restrict__ theta_ps,
    const float* __restrict__ rot_p, float* __restrict__ out)
{
    __shared__ float2 s[1024];
    __shared__ float red[40];
    int b = blockIdx.x;
    int tid = threadIdx.x;

    float a[10];
#pragma unroll
    for (int k = 0; k < 10; ++k) a[k] = ang[b * 10 + k];
    float th[10];
#pragma unroll
    for (int k = 0; k < 10; ++k) th[k] = theta0[k] + a[k];
    th[1] += a[1];
    th[5] -= 0.78539816339745f;   // RX(-pi/4) on wire 5

    float2 v[10][2];
#pragma unroll
    for (int k = 0; k < 10; ++k) {
        float c, sn; sincosf(0.5f * th[k], &sn, &c);
        v[k][0] = make_float2(c, 0.f);
        v[k][1] = make_float2(0.f, -sn);
    }
    { float c, sn; sincosf(0.5f * a[2], &sn, &c);
      float2 v0 = v[2][0], v1 = v[2][1];
      v[2][0] = make_float2(c * v0.x - sn * v1.x, c * v0.y - sn * v1.y);
      v[2][1] = make_float2(sn * v0.x + c * v1.x, sn * v0.y + c * v1.y); }
    { float c, sn; sincosf(0.5f * a[3], &sn, &c);
      v[3][0] = cmul(v[3][0], make_float2(c, -sn));
      v[3][1] = cmul(v[3][1], make_float2(c, sn)); }
    { float2 t = v[4][1]; v[4][1] = make_float2(-t.y, t.x); }
    { const float r = 0.70710678118655f;
      float2 t = v[5][1]; v[5][1] = make_float2(r * (t.x - t.y), r * (t.x + t.y)); }
    { float c, sn; sincosf(0.5f * theta_rz[0], &sn, &c);
      v[6][0] = cmul(v[6][0], make_float2(c, -sn));
      v[6][1] = cmul(v[6][1], make_float2(c, sn)); }
    { float2 p = v[7][0], q = v[7][1];
      v[7][0] = make_float2(0.5f * ((p.x - p.y) + (q.x + q.y)),
                            0.5f * ((p.x + p.y) + (q.y - q.x)));
      v[7][1] = make_float2(0.5f * ((p.x + p.y) + (q.x - q.y)),
                            0.5f * ((p.y - p.x) + (q.x + q.y))); }

    for (int i = tid; i < 1024; i += 256) {
        float2 c = v[0][(i >> 9) & 1];
#pragma unroll
        for (int k = 1; k < 10; ++k)
            c = cmul(c, v[k][(i >> (9 - k)) & 1]);
        s[i] = c;
    }
    __syncthreads();

    for (int i = tid; i < 1024; i += 256)
        if (((i >> 9) & 1) && ((i >> 4) & 1)) { s[i].x = -s[i].x; s[i].y = -s[i].y; }
    __syncthreads();
    { int j = tid;
      int i0 = 512 | ((j >> 4) << 5) | (j & 15);
      int i1 = i0 | 16;
      float2 t0 = s[i0], t1 = s[i1];
      s[i0] = t1; s[i1] = t0; }
    __syncthreads();
    { int j = tid;
      int i0 = 512 | ((j >> 4) << 5) | (j & 15);
      int i1 = i0 | 16;
      float2 t0 = s[i0], t1 = s[i1];
      s[i0] = make_float2(t1.y, -t1.x);
      s[i1] = make_float2(-t0.y, t0.x); }
    __syncthreads();
    { int j = tid;
      int i0 = (j & 1) | (((j >> 1) & 15) << 2) | (((j >> 5) & 7) << 7) | 64;
      int i1 = i0 | 2;
      float2 t0 = s[i0], t1 = s[i1];
      s[i0] = make_float2(t1.y, -t1.x);
      s[i1] = make_float2(-t0.y, t0.x); }
    __syncthreads();
    { int j = tid;
      int i0 = (j & 63) | 128 | (((j >> 6) & 3) << 8);
      int i1 = i0 ^ 0xC0;
      float2 t0 = s[i0], t1 = s[i1];
      s[i0] = t1; s[i1] = t0; }
    __syncthreads();
    if (tid < 128) {
      int j = tid;
      int i0 = (j & 7) | 16 | 32 | (((j >> 3) & 15) << 6);
      int i1 = i0 ^ 0x18;
      float2 t0 = s[i0], t1 = s[i1];
      s[i0] = t1; s[i1] = t0; }
    __syncthreads();
    if (tid < 128) {
      int j = tid;
      int i0 = (j & 1) | 2 | (((j >> 1) & 3) << 2) | 16 | (((j >> 3) & 15) << 5);
      int i1 = i0 | 512;
      float2 t0 = s[i0], t1 = s[i1];
      s[i0] = t1; s[i1] = t0; }
    __syncthreads();
    { float c1, s1; sincosf(theta_ps[0], &s1, &c1);
      float c2, s2; sincosf(a[7], &s2, &c2);
      float2 p1 = make_float2(c1, s1), p2 = make_float2(c2, s2);
      for (int i = tid; i < 1024; i += 256) {
          float2 t = s[i];
          if ((i >> 1) & 1) t = cmul(t, p1);
          if ((i >> 2) & 1) t = cmul(t, p2);
          s[i] = t;
      } }
    __syncthreads();
    apply_rot(s, 5, rot_p[0], rot_p[1], rot_p[2], tid);
    __syncthreads();
    apply_rot(s, 4, a[6], a[7], a[8], tid);
    __syncthreads();

    int wave = tid >> 6;
    for (int k = 0; k < 10; ++k) {
        int p = 9 - k;
        float part = 0.f;
        for (int q = tid; q < 512; q += 256) {
            int i0 = ((q >> p) << (p + 1)) | (q & ((1 << p) - 1));
            int i1 = i0 | (1 << p);
            float2 aa = s[i0], bb = s[i1];
            part += aa.x * bb.y - aa.y * bb.x;
        }
        part *= 2.f;
#pragma unroll
        for (int off = 32; off > 0; off >>= 1)
            part += __shfl_down(part, off, 64);
        if ((tid & 63) == 0) red[k * 4 + wave] = part;
    }
    __syncthreads();
    if (tid == 0) {
        float ev[10];
        float mx = -1e30f;
#pragma unroll
        for (int k = 0; k < 10; ++k) {
            ev[k] = red[k * 4] + red[k * 4 + 1] + red[k * 4 + 2] + red[k * 4 + 3];
            mx = fmaxf(mx, ev[k]);
        }
        float sum = 0.f;
#pragma unroll
        for (int k = 0; k < 10; ++k) sum += expf(ev[k] - mx);
        float lse = mx + logf(sum);
#pragma unroll
        for (int k = 0; k < 10; ++k) out[b * 10 + k] = ev[k] - lse;
    }
}

extern "C" void kernel_launch(void* const* d_in, const int* in_sizes, int n_in,
                              void* d_out, int out_size, void* d_ws, size_t ws_size,
                              hipStream_t stream)
{
    (void)in_sizes; (void)n_in; (void)out_size; (void)ws_size;
    const float* x    = (const float*)d_in[0];
    const float* c1w  = (const float*)d_in[1];
    const float* c1b  = (const float*)d_in[2];
    const float* c2w  = (const float*)d_in[3];
    const float* c2b  = (const float*)d_in[4];
    const float* f1w  = (const float*)d_in[5];
    const float* f1b  = (const float*)d_in[6];
    const float* f2w  = (const float*)d_in[7];
    const float* f2b  = (const float*)d_in[8];
    const float* th0  = (const float*)d_in[9];
    const float* trz  = (const float*)d_in[10];
    const float* tps  = (const float*)d_in[11];
    const float* rotp = (const float*)d_in[12];
    float* out = (float*)d_out;

    char* ws = (char*)d_ws;
    ushort* pooled = (ushort*)(ws);                       // 37,748,736 B
    ushort* wt2    = (ushort*)(ws + 37748736);            //     36,864 B
    ushort* wf1    = (ushort*)(ws + 37785600);            //  2,359,296 B
    float*  part   = (float*)(ws + 40144896);             //  4,194,304 B
    float*  fc1o   = (float*)(ws + 44339200);             //  1,048,576 B
    float*  ang    = (float*)(ws + 45387776);             //     81,920 B

    prep_kernel<<<4680, 256, 0, stream>>>(c2w, f1w, wt2, wf1);
    conv2_fused<<<2048, 384, 0, stream>>>(x, c1w, c1b, wt2, c2b, pooled);
    fc1_mfma<<<dim3(64, 4), 256, 0, stream>>>(pooled, wf1, part);
    fc1_reduce_kernel<<<1024, 256, 0, stream>>>(part, f1b, fc1o);
    fc2_kernel<<<80, 256, 0, stream>>>(fc1o, f2w, f2b, ang);
    quantum_kernel<<<2048, 256, 0, stream>>>(ang, th0, trz, tps, rotp, out);
}